// Round 2
// baseline (492.413 us; speedup 1.0000x reference)
//
#include <hip/hip_runtime.h>

#define NQT   300
#define HWT   4096
#define NHEAD 8
#define HDIM  32
#define QT     16
#define TK     64
#define NSPLIT 8
#define KSPLIT 512
#define NQB    19      // ceil(300/16)
#define RECSZ  544     // 16 m + 16 l + 16*32 acc

// ---------------------------------------------------------------------------
// Projection GEMM: Out[M x 256] = ((X [+ Xpos]) @ W + bias) * scale
// BM=128, BN=64, BK=16, 256 threads, 8x4 microtile. fp32.
// ---------------------------------------------------------------------------
__global__ __launch_bounds__(256) void proj_gemm(
    const float* __restrict__ X, const float* __restrict__ Xpos,
    const float* __restrict__ W, const float* __restrict__ bias,
    float* __restrict__ Out, int M, float scale)
{
    __shared__ float As[16][132];   // [k][row]
    __shared__ float Bs[16][64];    // [k][col]
    const int t  = threadIdx.x;
    const int m0 = blockIdx.x * 128;
    const int n0 = blockIdx.y * 64;
    const int rg = t >> 4, cg = t & 15;     // compute mapping
    const int lr = t >> 2, lc = t & 3;      // staging mapping

    float acc[8][4] = {};

    for (int k0 = 0; k0 < 256; k0 += 16) {
        float4 av[2];
        #pragma unroll
        for (int i = 0; i < 2; ++i) {
            const int gr = m0 + lr + 64 * i;
            if (gr < M) {
                av[i] = *(const float4*)(X + (size_t)gr * 256 + k0 + lc * 4);
                if (Xpos) {
                    float4 pv = *(const float4*)(Xpos + (size_t)gr * 256 + k0 + lc * 4);
                    av[i].x += pv.x; av[i].y += pv.y; av[i].z += pv.z; av[i].w += pv.w;
                }
            } else {
                av[i] = make_float4(0.f, 0.f, 0.f, 0.f);
            }
        }
        float4 bv = *(const float4*)(W + (size_t)(k0 + (t >> 4)) * 256 + n0 + (t & 15) * 4);

        __syncthreads();
        #pragma unroll
        for (int i = 0; i < 2; ++i) {
            const int row = lr + 64 * i;
            As[lc * 4 + 0][row] = av[i].x;
            As[lc * 4 + 1][row] = av[i].y;
            As[lc * 4 + 2][row] = av[i].z;
            As[lc * 4 + 3][row] = av[i].w;
        }
        *(float4*)&Bs[t >> 4][(t & 15) * 4] = bv;
        __syncthreads();

        #pragma unroll
        for (int k = 0; k < 16; ++k) {
            float4 a0 = *(const float4*)&As[k][rg * 8];
            float4 a1 = *(const float4*)&As[k][rg * 8 + 4];
            float4 b4 = *(const float4*)&Bs[k][cg * 4];
            float a[8] = {a0.x, a0.y, a0.z, a0.w, a1.x, a1.y, a1.z, a1.w};
            float bb[4] = {b4.x, b4.y, b4.z, b4.w};
            #pragma unroll
            for (int i = 0; i < 8; ++i)
                #pragma unroll
                for (int j = 0; j < 4; ++j)
                    acc[i][j] = fmaf(a[i], bb[j], acc[i][j]);
        }
    }

    float4 bb = *(const float4*)(bias + n0 + cg * 4);
    #pragma unroll
    for (int i = 0; i < 8; ++i) {
        int gr = m0 + rg * 8 + i;
        if (gr < M) {
            float4 o;
            o.x = (acc[i][0] + bb.x) * scale;
            o.y = (acc[i][1] + bb.y) * scale;
            o.z = (acc[i][2] + bb.z) * scale;
            o.w = (acc[i][3] + bb.w) * scale;
            *(float4*)(Out + (size_t)gr * 256 + n0 + cg * 4) = o;
        }
    }
}

// ---------------------------------------------------------------------------
// RPE tables (unchanged from round 1)
// ---------------------------------------------------------------------------
__global__ __launch_bounds__(256) void rpe_kernel(
    const float* __restrict__ refpts,
    const float* __restrict__ w1x, const float* __restrict__ b1x, const float* __restrict__ w2x,
    const float* __restrict__ w1y, const float* __restrict__ b1y, const float* __restrict__ w2y,
    float* __restrict__ outx, float* __restrict__ outy)
{
    const int axis = blockIdx.y;
    const int item = blockIdx.x * 256 + threadIdx.x;
    const int bq   = __builtin_amdgcn_readfirstlane(item >> 6);
    const int pos  = item & 63;

    const float* w1 = axis ? w1y : w1x;
    const float* b1 = axis ? b1y : b1x;
    const float* w2 = axis ? w2y : w2x;

    float4 r = *(const float4*)(refpts + (size_t)bq * 4);
    float ctr  = axis ? r.y : r.x;
    float half = (axis ? r.w : r.z) * 0.5f;
    float lo = (ctr - half) * 1024.f;
    float hi = (ctr + half) * 1024.f;
    float p  = ((float)pos + 0.5f) * 16.f;
    float d0 = lo - p, d1 = hi - p;

    float a0 = 0.f, a1 = 0.f, a2 = 0.f, a3 = 0.f;
    float a4 = 0.f, a5 = 0.f, a6 = 0.f, a7 = 0.f;

    #pragma unroll 4
    for (int hid = 0; hid < 512; ++hid) {
        float hv = fmaf(d0, w1[hid], fmaf(d1, w1[512 + hid], b1[hid]));
        hv = fmaxf(hv, 0.f);
        float4 wA = *(const float4*)(w2 + (size_t)hid * 8);
        float4 wB = *(const float4*)(w2 + (size_t)hid * 8 + 4);
        a0 = fmaf(hv, wA.x, a0); a1 = fmaf(hv, wA.y, a1);
        a2 = fmaf(hv, wA.z, a2); a3 = fmaf(hv, wA.w, a3);
        a4 = fmaf(hv, wB.x, a4); a5 = fmaf(hv, wB.y, a5);
        a6 = fmaf(hv, wB.z, a6); a7 = fmaf(hv, wB.w, a7);
    }

    float* op = (axis ? outy : outx) + (size_t)bq * 512 + pos;
    op[0]   = a0; op[64]  = a1; op[128] = a2; op[192] = a3;
    op[256] = a4; op[320] = a5; op[384] = a6; op[448] = a7;
}

// ---------------------------------------------------------------------------
// Split-K flash attention. Grid (19, 16, 8). Block 256 = 4 waves.
// Each block: 16 queries x 512 keys (8 tiles of 64), writes partial
// (m[16], l[16], acc[16][32]) record to `part`.
// Phase 1: thread (qp=t>>5, kg=t&31) owns 2 queries x 2 keys {kg, kg+32},
//          Q in registers (2x8 float4).
// Phase 3: slice s3=t>>5 owns 8 keys; lane (qg,dg) owns 4q x 4d.
// LDS 31 KB; final reduce buffer aliased over dead K/V/P tiles.
// ---------------------------------------------------------------------------
#define KS_O  0       // Ks  [64][36]  -> 2304
#define VST_O 2304    // VsT [32][68]  -> 2176 (XOR-swizzled col4)
#define PS_O  4480    // Ps  [16][68]  -> 1088
#define RX_O  5568    // Rx  [16][66]  -> 1056
#define RY_O  6624    // Ry  [16][66]  -> 1056
#define MSK_O 7680    // 64
#define CF_O  7744    // 16
#define SM_TOT 7760

__global__ __launch_bounds__(256, 4) void attn_split(
    const float* __restrict__ Q,    // [B][300][256] pre-scaled
    const float* __restrict__ K,    // [B][4096][256]
    const float* __restrict__ V,    // [B][4096][256]
    const float* __restrict__ RPX,  // [B*300][8][64]
    const float* __restrict__ RPY,  // [B*300][8][64]
    const float* __restrict__ mask, // [B][4096]
    float* __restrict__ part)
{
    __shared__ float sm[SM_TOT];

    const int bh = blockIdx.y;
    const int b  = bh >> 3, h = bh & 7;
    const int qb0 = blockIdx.x;
    const int q0  = qb0 * QT;
    const int split = blockIdx.z;
    const int kbase = split * KSPLIT;
    const int t  = threadIdx.x;
    const int qp = t >> 5;        // 0..7 (phase 1)
    const int kg = t & 31;
    const int s3 = t >> 5;        // 0..7 (phase 3 key slice)
    const int qg = (t >> 3) & 3;  // query group (4q)
    const int dg = t & 7;         // dim group (4d)

    // Q rows (2 per thread) into registers
    float4 qreg[2][8];
    #pragma unroll
    for (int j = 0; j < 2; ++j) {
        int qr = q0 + 2 * qp + j;
        if (qr >= NQT) qr = NQT - 1;
        const float* qptr = Q + ((size_t)(b * NQT + qr)) * 256 + h * HDIM;
        #pragma unroll
        for (int c = 0; c < 8; ++c) qreg[j][c] = *(const float4*)(qptr + c * 4);
    }

    // RPE tiles
    for (int i = t; i < QT * 64; i += 256) {
        int qq = i >> 6, x = i & 63;
        int qr = q0 + qq; if (qr >= NQT) qr = NQT - 1;
        size_t base = ((size_t)(b * NQT + qr) * 8 + h) * 64 + x;
        sm[RX_O + qq * 66 + x] = RPX[base];
        sm[RY_O + qq * 66 + x] = RPY[base];
    }

    float m0r = -1e30f, m1r = -1e30f, l0r = 0.f, l1r = 0.f;
    float accq[4][4] = {};

    for (int k0 = 0; k0 < KSPLIT; k0 += TK) {
        __syncthreads();   // previous phase-3 / RPE-store done

        // ---- stage K (row-major, pad 36) and V^T (swizzled), mask ----
        #pragma unroll
        for (int i = 0; i < 2; ++i) {
            int j = t + 256 * i;
            int kk = j >> 3, seg = j & 7;
            size_t goff = ((size_t)(b * HWT + kbase + k0 + kk)) * 256 + h * HDIM + seg * 4;
            float4 kv = *(const float4*)(K + goff);
            float4 vv = *(const float4*)(V + goff);
            *(float4*)&sm[KS_O + kk * 36 + seg * 4] = kv;
            int cb = ((kk >> 2) ^ (seg & 3)) * 4 + (kk & 3);   // swizzled col
            sm[VST_O + (seg * 4 + 0) * 68 + cb] = vv.x;
            sm[VST_O + (seg * 4 + 1) * 68 + cb] = vv.y;
            sm[VST_O + (seg * 4 + 2) * 68 + cb] = vv.z;
            sm[VST_O + (seg * 4 + 3) * 68 + cb] = vv.w;
        }
        if (t < TK) sm[MSK_O + t] = mask[(size_t)b * HWT + kbase + k0 + t];
        __syncthreads();

        // ---- phase 1: 2q x 2k logits + online softmax ----
        float sv0[2], sv1[2];
        #pragma unroll
        for (int i = 0; i < 2; ++i) {
            const int kk = kg + 32 * i;
            const float* kp = &sm[KS_O + kk * 36];
            float d0 = 0.f, d1 = 0.f;
            #pragma unroll
            for (int c = 0; c < 8; ++c) {
                float4 kv = *(const float4*)(kp + c * 4);
                d0 = fmaf(qreg[0][c].x, kv.x, d0);
                d0 = fmaf(qreg[0][c].y, kv.y, d0);
                d0 = fmaf(qreg[0][c].z, kv.z, d0);
                d0 = fmaf(qreg[0][c].w, kv.w, d0);
                d1 = fmaf(qreg[1][c].x, kv.x, d1);
                d1 = fmaf(qreg[1][c].y, kv.y, d1);
                d1 = fmaf(qreg[1][c].z, kv.z, d1);
                d1 = fmaf(qreg[1][c].w, kv.w, d1);
            }
            const int kgl = kbase + k0 + kk;
            const int xl = kgl & 63, yl = kgl >> 6;
            const float mk = sm[MSK_O + kk] * (-100.f);
            sv0[i] = d0 + sm[RX_O + (2 * qp) * 66 + xl] + sm[RY_O + (2 * qp) * 66 + yl] + mk;
            sv1[i] = d1 + sm[RX_O + (2 * qp + 1) * 66 + xl] + sm[RY_O + (2 * qp + 1) * 66 + yl] + mk;
        }
        float t0 = fmaxf(sv0[0], sv0[1]);
        float t1 = fmaxf(sv1[0], sv1[1]);
        #pragma unroll
        for (int off = 16; off; off >>= 1) {
            t0 = fmaxf(t0, __shfl_xor(t0, off));
            t1 = fmaxf(t1, __shfl_xor(t1, off));
        }
        const float mn0 = fmaxf(m0r, t0), mn1 = fmaxf(m1r, t1);
        const float c0 = __expf(m0r - mn0), c1 = __expf(m1r - mn1);
        const float p00 = __expf(sv0[0] - mn0), p01 = __expf(sv0[1] - mn0);
        const float p10 = __expf(sv1[0] - mn1), p11 = __expf(sv1[1] - mn1);
        sm[PS_O + (2 * qp) * 68 + kg]          = p00;
        sm[PS_O + (2 * qp) * 68 + kg + 32]     = p01;
        sm[PS_O + (2 * qp + 1) * 68 + kg]      = p10;
        sm[PS_O + (2 * qp + 1) * 68 + kg + 32] = p11;
        float s0 = p00 + p01, s1 = p10 + p11;
        #pragma unroll
        for (int off = 16; off; off >>= 1) {
            s0 += __shfl_xor(s0, off);
            s1 += __shfl_xor(s1, off);
        }
        l0r = l0r * c0 + s0; l1r = l1r * c1 + s1;
        m0r = mn0; m1r = mn1;
        if (kg == 0) { sm[CF_O + 2 * qp] = c0; sm[CF_O + 2 * qp + 1] = c1; }
        __syncthreads();

        // ---- phase 3: PV over this slice's 8 keys, 4q x 4d per lane ----
        float cf[4];
        #pragma unroll
        for (int i = 0; i < 4; ++i) cf[i] = sm[CF_O + qg * 4 + i];
        #pragma unroll
        for (int i = 0; i < 4; ++i)
            #pragma unroll
            for (int d = 0; d < 4; ++d) accq[i][d] *= cf[i];

        const int ks0 = s3 * 8;
        #pragma unroll
        for (int kc = 0; kc < 8; kc += 4) {
            const int kk = ks0 + kc;
            float4 pv[4], vv[4];
            #pragma unroll
            for (int i = 0; i < 4; ++i)
                pv[i] = *(const float4*)&sm[PS_O + (qg * 4 + i) * 68 + kk];
            const int p4 = ((kk >> 2) ^ (dg & 3)) * 4;
            #pragma unroll
            for (int d = 0; d < 4; ++d)
                vv[d] = *(const float4*)&sm[VST_O + (dg * 4 + d) * 68 + p4];
            #pragma unroll
            for (int i = 0; i < 4; ++i)
                #pragma unroll
                for (int d = 0; d < 4; ++d) {
                    accq[i][d] = fmaf(pv[i].x, vv[d].x, accq[i][d]);
                    accq[i][d] = fmaf(pv[i].y, vv[d].y, accq[i][d]);
                    accq[i][d] = fmaf(pv[i].z, vv[d].z, accq[i][d]);
                    accq[i][d] = fmaf(pv[i].w, vv[d].w, accq[i][d]);
                }
        }
    }

    const size_t rec = ((size_t)(bh * NQB + qb0) * NSPLIT + split) * RECSZ;
    if (kg == 0) {
        part[rec + 2 * qp]      = m0r;
        part[rec + 2 * qp + 1]  = m1r;
        part[rec + 16 + 2 * qp]     = l0r;
        part[rec + 16 + 2 * qp + 1] = l1r;
    }
    __syncthreads();   // all phase-3 reads of Ks/VsT/Ps done

    // cross-slice reduction buffer aliased over Ks/VsT/Ps (stride 36 per q)
    #pragma unroll
    for (int i = 0; i < 4; ++i)
        *(float4*)&sm[s3 * 576 + (qg * 4 + i) * 36 + dg * 4] =
            make_float4(accq[i][0], accq[i][1], accq[i][2], accq[i][3]);
    __syncthreads();

    {
        const int q = t >> 4, d2 = (t & 15) * 2;
        float r0 = 0.f, r1 = 0.f;
        #pragma unroll
        for (int s = 0; s < 8; ++s) {
            r0 += sm[s * 576 + q * 36 + d2];
            r1 += sm[s * 576 + q * 36 + d2 + 1];
        }
        *(float2*)&part[rec + 32 + q * 32 + d2] = make_float2(r0, r1);
    }
}

// ---------------------------------------------------------------------------
// Combine split partials: out = sum_s exp(m_s-M) acc_s / sum_s exp(m_s-M) l_s
// ---------------------------------------------------------------------------
__global__ __launch_bounds__(256) void attn_combine(
    const float* __restrict__ part, float* __restrict__ Xout)
{
    const int gi  = blockIdx.x * 256 + threadIdx.x;   // 0..153599
    const int d   = gi & 31;
    const int row = gi >> 5;                          // 0..4799
    const int bh  = row / NQT;
    const int q   = row - bh * NQT;
    const int qblk = q >> 4, qi = q & 15;
    const float* rp = part + ((size_t)(bh * NQB + qblk) * NSPLIT) * RECSZ;

    float mv[NSPLIT], lv[NSPLIT];
    float M = -1e30f;
    #pragma unroll
    for (int s = 0; s < NSPLIT; ++s) {
        mv[s] = rp[s * RECSZ + qi];
        lv[s] = rp[s * RECSZ + 16 + qi];
        M = fmaxf(M, mv[s]);
    }
    float num = 0.f, den = 0.f;
    #pragma unroll
    for (int s = 0; s < NSPLIT; ++s) {
        float w = __expf(mv[s] - M);
        den = fmaf(w, lv[s], den);
        num = fmaf(w, rp[s * RECSZ + 32 + qi * 32 + d], num);
    }
    const int b = bh >> 3, h = bh & 7;
    Xout[((size_t)(b * NQT + q)) * 256 + h * HDIM + d] = num / den;
}

// ---------------------------------------------------------------------------
extern "C" void kernel_launch(void* const* d_in, const int* in_sizes, int n_in,
                              void* d_out, int out_size, void* d_ws, size_t ws_size,
                              hipStream_t stream)
{
    (void)in_sizes; (void)n_in; (void)out_size; (void)ws_size;

    const float* raw_query = (const float*)d_in[0];
    const float* query_pos = (const float*)d_in[1];
    const float* refpts    = (const float*)d_in[2];
    const float* raw_src   = (const float*)d_in[3];
    const float* src_pos   = (const float*)d_in[4];
    const float* mask      = (const float*)d_in[5];
    const float* Wq = (const float*)d_in[7];
    const float* bq = (const float*)d_in[8];
    const float* Wk = (const float*)d_in[9];
    const float* bk = (const float*)d_in[10];
    const float* Wv = (const float*)d_in[11];
    const float* bv = (const float*)d_in[12];
    const float* Wp = (const float*)d_in[13];
    const float* bp = (const float*)d_in[14];
    const float* c1w1 = (const float*)d_in[15];
    const float* c1b1 = (const float*)d_in[16];
    const float* c1w2 = (const float*)d_in[17];
    const float* c2w1 = (const float*)d_in[18];
    const float* c2b1 = (const float*)d_in[19];
    const float* c2w2 = (const float*)d_in[20];

    float* ws = (float*)d_ws;
    float* Qf   = ws;                   // 600*256    = 153600
    float* Kf   = Qf + 153600;          // 8192*256   = 2097152
    float* Vf   = Kf + 2097152;         // 2097152
    float* RX   = Vf + 2097152;         // 307200
    float* RY   = RX + 307200;          // 307200
    float* Xf   = RY + 307200;          // 153600
    float* PART = Xf + 153600;          // 16*19*8*544 = 1322496

    dim3 blk(256);
    const float qscale = 0.17677669529663687f;  // 32^-0.5

    proj_gemm<<<dim3(5, 4),  blk, 0, stream>>>(raw_query, query_pos, Wq, bq, Qf, 600,  qscale);
    proj_gemm<<<dim3(64, 4), blk, 0, stream>>>(raw_src,   src_pos,   Wk, bk, Kf, 8192, 1.f);
    proj_gemm<<<dim3(64, 4), blk, 0, stream>>>(raw_src,   nullptr,   Wv, bv, Vf, 8192, 1.f);
    rpe_kernel<<<dim3(150, 2), blk, 0, stream>>>(refpts, c1w1, c1b1, c1w2, c2w1, c2b1, c2w2, RX, RY);
    attn_split<<<dim3(NQB, 16, NSPLIT), blk, 0, stream>>>(Qf, Kf, Vf, RX, RY, mask, PART);
    attn_combine<<<dim3(600), blk, 0, stream>>>(PART, Xf);
    proj_gemm<<<dim3(5, 4),  blk, 0, stream>>>(Xf, nullptr, Wp, bp, (float*)d_out, 600, 1.f);
}